// Round 2
// baseline (791.538 us; speedup 1.0000x reference)
//
#include <hip/hip_runtime.h>

// ---------------------------------------------------------------------------
// PlaneEmbeddingNetwork, round 2.
// R1 post-mortem: latency-bound (VALUBusy 51%, occupancy 19.8%, FETCH 204MB
// from random node gathers). Fixes:
//  1. No LDS: pooled->out fused inline (oacc2 accumulators), removes the
//     32KB/block occupancy cap and the barrier-free LDS round trip.
//  2. Packed fp32 (v_pk_fma_f32 via float2 ext-vectors +
//     __builtin_elementwise_fma): halves VALU issue slots; fp32 peak on
//     CDNA4 requires packed ops.
//  3. __launch_bounds__(256,4): VGPR<=128 -> 4 waves/SIMD step (m69).
// W1 is stored TRANSPOSED ([c][d], 64B rows) so pooled reads are contiguous
// uniform s_loads.
// ---------------------------------------------------------------------------

typedef float v2f __attribute__((ext_vector_type(2)));

static __device__ __forceinline__ v2f splat2(float x) {
    v2f r; r.x = x; r.y = x; return r;
}
static __device__ __forceinline__ v2f fma2(v2f a, v2f b, v2f c) {
    return __builtin_elementwise_fma(a, b, c);
}

// Setup: W1T[c][d] = sum_e w_out[d*16+e] * fc_w[e*32+c]   -> ws[c*16+d], c<32,d<16
//        b1[c]     = sum_e b_out[e] * fc_w[e*32+c] + fc_b[c] -> ws[512+c]
__global__ void fold_w1(const float* __restrict__ w_out,
                        const float* __restrict__ b_out,
                        const float* __restrict__ fc_w,
                        const float* __restrict__ fc_b,
                        float* __restrict__ ws) {
    int tid = threadIdx.x;
    if (tid < 512) {
        int c = tid >> 4, d = tid & 15;
        float acc = 0.f;
#pragma unroll
        for (int e = 0; e < 16; ++e)
            acc = fmaf(w_out[d * 16 + e], fc_w[e * 32 + c], acc);
        ws[c * 16 + d] = acc;
    } else if (tid < 544) {
        int c = tid - 512;
        float acc = fc_b[c];
#pragma unroll
        for (int e = 0; e < 16; ++e)
            acc = fmaf(b_out[e], fc_w[e * 32 + c], acc);
        ws[512 + c] = acc;
    }
}

__launch_bounds__(256, 4)
__global__ void face_net(const float* __restrict__ node,
                         const int*   __restrict__ fids,
                         const float* __restrict__ w_in,
                         const float* __restrict__ b_in,
                         const float* __restrict__ w1b1,   // ws: W1T[32][16], b1[32]
                         const float* __restrict__ fco_w,
                         const float* __restrict__ fco_b,
                         float* __restrict__ out, int F) {
    const int f = blockIdx.x * 256 + threadIdx.x;
    if (f >= F) return;

    const int4 id4 = *reinterpret_cast<const int4*>(fids + (size_t)f * 4);
    const float* xp0 = node + (size_t)id4.x * 16;
    const float* xp1 = node + (size_t)id4.y * 16;
    const float* xp2 = node + (size_t)id4.z * 16;
    const float* xp3 = node + (size_t)id4.w * 16;

    // ---- qkv projection (packed pairs): q/k/v as [4 tokens][8 float2].
    // k-bias dropped (softmax row-constant).
    const v2f* b_in2 = reinterpret_cast<const v2f*>(b_in);
    v2f q2[4][8], k2[4][8], v2[4][8];
#pragma unroll
    for (int o = 0; o < 8; ++o) {
        const v2f bq = b_in2[o], bv = b_in2[16 + o];
        const v2f z = splat2(0.f);
#pragma unroll
        for (int t = 0; t < 4; ++t) { q2[t][o] = bq; k2[t][o] = z; v2[t][o] = bv; }
    }

#pragma unroll
    for (int cc = 0; cc < 4; ++cc) {
        const float4 x0 = *reinterpret_cast<const float4*>(xp0 + cc * 4);
        const float4 x1 = *reinterpret_cast<const float4*>(xp1 + cc * 4);
        const float4 x2 = *reinterpret_cast<const float4*>(xp2 + cc * 4);
        const float4 x3 = *reinterpret_cast<const float4*>(xp3 + cc * 4);
        const float xa[4][4] = {{x0.x, x0.y, x0.z, x0.w},
                                {x1.x, x1.y, x1.z, x1.w},
                                {x2.x, x2.y, x2.z, x2.w},
                                {x3.x, x3.y, x3.z, x3.w}};
#pragma unroll
        for (int dd = 0; dd < 4; ++dd) {
            // uniform -> s_load pairs
            const v2f* wrow2 = reinterpret_cast<const v2f*>(w_in + (cc * 4 + dd) * 48);
#pragma unroll
            for (int o = 0; o < 8; ++o) {
                const v2f wq = wrow2[o], wk = wrow2[8 + o], wv = wrow2[16 + o];
#pragma unroll
                for (int t = 0; t < 4; ++t) {
                    const v2f xs = splat2(xa[t][dd]);
                    q2[t][o] = fma2(xs, wq, q2[t][o]);
                    k2[t][o] = fma2(xs, wk, k2[t][o]);
                    v2[t][o] = fma2(xs, wv, v2[t][o]);
                }
            }
        }
    }

    // ---- attention per head (head h owns pair-range [h*4, h*4+4) )
    v2f o2[4][8];
    const float scale = 0.35355339059327373f;  // 1/sqrt(8)
#pragma unroll
    for (int h = 0; h < 2; ++h) {
        const int hb = h * 4;
        float p[4][4];
#pragma unroll
        for (int t = 0; t < 4; ++t) {
#pragma unroll
            for (int j = 0; j < 4; ++j) {
                v2f a = q2[t][hb] * k2[j][hb];
#pragma unroll
                for (int d = 1; d < 4; ++d)
                    a = fma2(q2[t][hb + d], k2[j][hb + d], a);
                p[t][j] = (a.x + a.y) * scale;
            }
            const float m = fmaxf(fmaxf(p[t][0], p[t][1]), fmaxf(p[t][2], p[t][3]));
            float sum = 0.f;
#pragma unroll
            for (int j = 0; j < 4; ++j) { p[t][j] = __expf(p[t][j] - m); sum += p[t][j]; }
            const float r = __builtin_amdgcn_rcpf(sum);
#pragma unroll
            for (int j = 0; j < 4; ++j) p[t][j] *= r;
        }
#pragma unroll
        for (int t = 0; t < 4; ++t)
#pragma unroll
            for (int d = 0; d < 4; ++d) {
                v2f acc = splat2(p[t][0]) * v2[0][hb + d];
#pragma unroll
                for (int j = 1; j < 4; ++j)
                    acc = fma2(splat2(p[t][j]), v2[j][hb + d], acc);
                o2[t][hb + d] = acc;
            }
    }

    // ---- fused pooled+out: for each channel c, pooled_c then fma into oacc2.
    const v2f* fco_b2 = reinterpret_cast<const v2f*>(fco_b);
    v2f oacc2[16];
#pragma unroll
    for (int j = 0; j < 16; ++j) oacc2[j] = fco_b2[j];

#pragma unroll 1
    for (int c = 0; c < 32; ++c) {
        const v2f* w1r = reinterpret_cast<const v2f*>(w1b1 + c * 16);  // uniform, 64B row
        const float b1c = w1b1[512 + c];
        float s = 0.f;
#pragma unroll
        for (int t = 0; t < 4; ++t) {
            v2f a = o2[t][0] * w1r[0];
#pragma unroll
            for (int d = 1; d < 8; ++d)
                a = fma2(o2[t][d], w1r[d], a);
            s += fmaxf(a.x + a.y + b1c, 0.f);
        }
        const float pc = s * 0.25f;
        const v2f* fr = reinterpret_cast<const v2f*>(fco_w + c * 32);  // uniform
        const v2f ps = splat2(pc);
#pragma unroll
        for (int j = 0; j < 16; ++j)
            oacc2[j] = fma2(ps, fr[j], oacc2[j]);
    }

    float* op = out + (size_t)f * 32;
#pragma unroll
    for (int g = 0; g < 8; ++g) {
        const float4 w4 = make_float4(oacc2[g * 2].x, oacc2[g * 2].y,
                                      oacc2[g * 2 + 1].x, oacc2[g * 2 + 1].y);
        *reinterpret_cast<float4*>(op + g * 4) = w4;
    }
}

extern "C" void kernel_launch(void* const* d_in, const int* in_sizes, int n_in,
                              void* d_out, int out_size, void* d_ws, size_t ws_size,
                              hipStream_t stream) {
    const float* node  = (const float*)d_in[0];
    const int*   fids  = (const int*)  d_in[1];
    const float* w_in  = (const float*)d_in[2];
    const float* b_in  = (const float*)d_in[3];
    const float* w_out = (const float*)d_in[4];
    const float* b_out = (const float*)d_in[5];
    const float* fc_w  = (const float*)d_in[6];
    const float* fc_b  = (const float*)d_in[7];
    const float* fco_w = (const float*)d_in[8];
    const float* fco_b = (const float*)d_in[9];
    float* out = (float*)d_out;
    float* ws  = (float*)d_ws;
    const int F = in_sizes[1] / 4;

    hipLaunchKernelGGL(fold_w1, dim3(1), dim3(576), 0, stream,
                       w_out, b_out, fc_w, fc_b, ws);
    const int blocks = (F + 255) / 256;
    hipLaunchKernelGGL(face_net, dim3(blocks), dim3(256), 0, stream,
                       node, fids, w_in, b_in, ws, fco_w, fco_b, out, F);
}

// Round 4
// 191.916 us; speedup vs baseline: 4.1244x; 4.1244x over previous
//
#include <hip/hip_runtime.h>

// ---------------------------------------------------------------------------
// PlaneEmbeddingNetwork, round 4.
// R3 post-mortem: DPP (mov_dpp quad_perm) attention failed correctness; the
// rotation algebra itself is provably direction-invariant, so the suspect is
// mov_dpp codegen (update_dpp old=undef lowering). This round: identical
// structure (4 lanes per face, one per token; ~70 VGPR live; no LDS arrays;
// no barriers) but ALL cross-lane traffic via __shfl/__shfl_xor width=4
// (ds_bpermute - unambiguous semantics). Shuffles gather from the ORIGINAL
// k/v registers (src=(t+r)&3), no serial rotation chains.
// __launch_bounds__(256,3): VGPR cap 85 (R2 lesson: cap = 256/min_waves);
// live set ~75 -> no spill expected. WRITE_SIZE >> 63MB would falsify.
// ---------------------------------------------------------------------------

typedef float v2f __attribute__((ext_vector_type(2)));

static __device__ __forceinline__ v2f splat2(float x) { v2f r; r.x = x; r.y = x; return r; }
static __device__ __forceinline__ v2f fma2(v2f a, v2f b, v2f c) {
    return __builtin_elementwise_fma(a, b, c);
}

// Setup: W1T[c][d] = sum_e w_out[d*16+e] * fc_w[e*32+c]   -> ws[c*16+d]
//        b1[c]     = sum_e b_out[e] * fc_w[e*32+c] + fc_b[c] -> ws[512+c]
__global__ void fold_w1(const float* __restrict__ w_out,
                        const float* __restrict__ b_out,
                        const float* __restrict__ fc_w,
                        const float* __restrict__ fc_b,
                        float* __restrict__ ws) {
    int tid = threadIdx.x;
    if (tid < 512) {
        int c = tid >> 4, d = tid & 15;
        float acc = 0.f;
#pragma unroll
        for (int e = 0; e < 16; ++e)
            acc = fmaf(w_out[d * 16 + e], fc_w[e * 32 + c], acc);
        ws[c * 16 + d] = acc;
    } else if (tid < 544) {
        int c = tid - 512;
        float acc = fc_b[c];
#pragma unroll
        for (int e = 0; e < 16; ++e)
            acc = fmaf(b_out[e], fc_w[e * 32 + c], acc);
        ws[512 + c] = acc;
    }
}

__launch_bounds__(256, 3)
__global__ void face_net(const float* __restrict__ node,
                         const int*   __restrict__ fids,
                         const float* __restrict__ w_in,
                         const float* __restrict__ b_in,
                         const float* __restrict__ w1b1,   // ws: W1T[32][16], b1[32]
                         const float* __restrict__ fco_w,
                         const float* __restrict__ fco_b,
                         float* __restrict__ out, int F) {
    const int g = blockIdx.x * 256 + threadIdx.x;
    const int f = g >> 2;
    if (f >= F) return;               // whole quads exit together (face-aligned)
    const int t = g & 3;

    // ---- gather own token's embedding (coalesced id load; 64B row fetch)
    const int nid = fids[g];
    const float* xp = node + (size_t)nid * 16;
    const float4 xv0 = *reinterpret_cast<const float4*>(xp);
    const float4 xv1 = *reinterpret_cast<const float4*>(xp + 4);
    const float4 xv2 = *reinterpret_cast<const float4*>(xp + 8);
    const float4 xv3 = *reinterpret_cast<const float4*>(xp + 12);
    const float xa[16] = {xv0.x, xv0.y, xv0.z, xv0.w, xv1.x, xv1.y, xv1.z, xv1.w,
                          xv2.x, xv2.y, xv2.z, xv2.w, xv3.x, xv3.y, xv3.z, xv3.w};

    // ---- qkv projection for OWN token (packed). k-bias dropped (softmax
    //      row-constant: score[t][j] = q_t.k_j + q_t.bk, const over j).
    const v2f* b2 = reinterpret_cast<const v2f*>(b_in);
    v2f q[8], k[8], v[8];
#pragma unroll
    for (int o = 0; o < 8; ++o) { q[o] = b2[o]; k[o] = splat2(0.f); v[o] = b2[16 + o]; }
#pragma unroll
    for (int d = 0; d < 16; ++d) {
        const v2f* wr = reinterpret_cast<const v2f*>(w_in + d * 48);  // uniform s_load
        const v2f xs = splat2(xa[d]);
#pragma unroll
        for (int o = 0; o < 8; ++o) {
            q[o] = fma2(xs, wr[o],      q[o]);
            k[o] = fma2(xs, wr[8 + o],  k[o]);
            v[o] = fma2(xs, wr[16 + o], v[o]);
        }
    }

    // ---- scores: p{h}[r] = q_t . k_{(t+r)%4} (head h), gathered via __shfl
    //      from the ORIGINAL k (no rotation chains). Softmax over r covers
    //      all j; PV uses the identical r->j mapping, so any consistent
    //      lane bijection is correct.
    const float scale = 0.35355339059327373f;  // 1/sqrt(8)
    float p0[4], p1[4];
    {   // r = 0: self, no shuffle
        v2f a0 = q[0] * k[0];
        v2f a1 = q[4] * k[4];
#pragma unroll
        for (int d = 1; d < 4; ++d) {
            a0 = fma2(q[d], k[d], a0);
            a1 = fma2(q[4 + d], k[4 + d], a1);
        }
        p0[0] = (a0.x + a0.y) * scale;
        p1[0] = (a1.x + a1.y) * scale;
    }
#pragma unroll
    for (int r = 1; r < 4; ++r) {
        const int src = (t + r) & 3;
        v2f kr[8];
#pragma unroll
        for (int d = 0; d < 8; ++d) {
            kr[d].x = __shfl(k[d].x, src, 4);
            kr[d].y = __shfl(k[d].y, src, 4);
        }
        v2f a0 = q[0] * kr[0];
        v2f a1 = q[4] * kr[4];
#pragma unroll
        for (int d = 1; d < 4; ++d) {
            a0 = fma2(q[d], kr[d], a0);
            a1 = fma2(q[4 + d], kr[4 + d], a1);
        }
        p0[r] = (a0.x + a0.y) * scale;
        p1[r] = (a1.x + a1.y) * scale;
    }
    {   // softmax per head (in-lane, 4 entries)
        const float m0 = fmaxf(fmaxf(p0[0], p0[1]), fmaxf(p0[2], p0[3]));
        const float m1 = fmaxf(fmaxf(p1[0], p1[1]), fmaxf(p1[2], p1[3]));
        float s0 = 0.f, s1 = 0.f;
#pragma unroll
        for (int j = 0; j < 4; ++j) {
            p0[j] = __expf(p0[j] - m0); s0 += p0[j];
            p1[j] = __expf(p1[j] - m1); s1 += p1[j];
        }
        const float r0 = __builtin_amdgcn_rcpf(s0);
        const float r1 = __builtin_amdgcn_rcpf(s1);
#pragma unroll
        for (int j = 0; j < 4; ++j) { p0[j] *= r0; p1[j] *= r1; }
    }

    // ---- PV: o_t = sum_r p[r] * v_{(t+r)%4}, v gathered from original regs
    v2f o[8];
#pragma unroll
    for (int d = 0; d < 4; ++d) {
        o[d]     = splat2(p0[0]) * v[d];
        o[4 + d] = splat2(p1[0]) * v[4 + d];
    }
#pragma unroll
    for (int r = 1; r < 4; ++r) {
        const int src = (t + r) & 3;
        const v2f ps0 = splat2(p0[r]), ps1 = splat2(p1[r]);
#pragma unroll
        for (int d = 0; d < 8; ++d) {
            v2f vr;
            vr.x = __shfl(v[d].x, src, 4);
            vr.y = __shfl(v[d].y, src, 4);
            if (d < 4) o[d]     = fma2(ps0, vr, o[d]);
            else       o[d]     = fma2(ps1, vr, o[d]);
        }
    }

    // ---- fused: h_t[c] = relu(o_t . W1T[c] + b1[c]); pooled_c = quadsum/4;
    //      each lane accumulates its own 8 output columns [t*8, t*8+8).
    const int t8 = t * 8;
    const float4 ob0 = *reinterpret_cast<const float4*>(fco_b + t8);
    const float4 ob1 = *reinterpret_cast<const float4*>(fco_b + t8 + 4);
    float oacc[8] = {ob0.x, ob0.y, ob0.z, ob0.w, ob1.x, ob1.y, ob1.z, ob1.w};

#pragma unroll 4
    for (int c = 0; c < 32; ++c) {
        const v2f* w1r = reinterpret_cast<const v2f*>(w1b1 + c * 16);  // uniform
        v2f a = o[0] * w1r[0];
#pragma unroll
        for (int d = 1; d < 8; ++d) a = fma2(o[d], w1r[d], a);
        const float h = fmaxf(a.x + a.y + w1b1[512 + c], 0.f);
        float s = h + __shfl_xor(h, 1, 4);
        s = s + __shfl_xor(s, 2, 4);
        const float pc = s * 0.25f;
        // lane-varying columns of fco_w: 4KB table, L1-resident
        const float4 f0 = *reinterpret_cast<const float4*>(fco_w + c * 32 + t8);
        const float4 f1 = *reinterpret_cast<const float4*>(fco_w + c * 32 + t8 + 4);
        oacc[0] = fmaf(pc, f0.x, oacc[0]); oacc[1] = fmaf(pc, f0.y, oacc[1]);
        oacc[2] = fmaf(pc, f0.z, oacc[2]); oacc[3] = fmaf(pc, f0.w, oacc[3]);
        oacc[4] = fmaf(pc, f1.x, oacc[4]); oacc[5] = fmaf(pc, f1.y, oacc[5]);
        oacc[6] = fmaf(pc, f1.z, oacc[6]); oacc[7] = fmaf(pc, f1.w, oacc[7]);
    }

    // ---- store: 16B/lane, contiguous across the quad and wave
    float* op = out + (size_t)f * 32 + t8;
    *reinterpret_cast<float4*>(op)     = make_float4(oacc[0], oacc[1], oacc[2], oacc[3]);
    *reinterpret_cast<float4*>(op + 4) = make_float4(oacc[4], oacc[5], oacc[6], oacc[7]);
}

extern "C" void kernel_launch(void* const* d_in, const int* in_sizes, int n_in,
                              void* d_out, int out_size, void* d_ws, size_t ws_size,
                              hipStream_t stream) {
    const float* node  = (const float*)d_in[0];
    const int*   fids  = (const int*)  d_in[1];
    const float* w_in  = (const float*)d_in[2];
    const float* b_in  = (const float*)d_in[3];
    const float* w_out = (const float*)d_in[4];
    const float* b_out = (const float*)d_in[5];
    const float* fc_w  = (const float*)d_in[6];
    const float* fc_b  = (const float*)d_in[7];
    const float* fco_w = (const float*)d_in[8];
    const float* fco_b = (const float*)d_in[9];
    float* out = (float*)d_out;
    float* ws  = (float*)d_ws;
    const int F = in_sizes[1] / 4;

    hipLaunchKernelGGL(fold_w1, dim3(1), dim3(576), 0, stream,
                       w_out, b_out, fc_w, fc_b, ws);
    const int threads = F * 4;
    const int blocks = (threads + 255) / 256;
    hipLaunchKernelGGL(face_net, dim3(blocks), dim3(256), 0, stream,
                       node, fids, w_in, b_in, ws, fco_w, fco_b, out, F);
}